// Round 1
// baseline (112.618 us; speedup 1.0000x reference)
//
#include <hip/hip_runtime.h>
#include <math.h>

// MultiInnerProductDecoder: out[t,e] = sigmoid( sum_d z[src[t,e],d] * z[dst[t,e],d] * weight[t,d] )
// z: [N_NODES,128] f32, weight: [8,128] f32, edge_src/dst: [8,E] int, out: [8,E] f32
//
// Decomposition: 32 lanes per edge. Lane l loads float4 element l of the
// 128-float rows (32 * float4 = 128 floats = one fully coalesced 512B row).
// Butterfly shfl_xor reduce within the 32-lane group; lane 0 writes sigmoid.
// blockIdx.y = edge type t (avoids per-edge integer division for t).

__global__ __launch_bounds__(256) void mipd_kernel(
    const float* __restrict__ z,
    const float* __restrict__ weight,
    const int*   __restrict__ edge_src,
    const int*   __restrict__ edge_dst,
    float*       __restrict__ out,
    int E)
{
    const int lane   = threadIdx.x & 31;           // position within 32-lane group
    const int gid    = (blockIdx.x * blockDim.x + threadIdx.x) >> 5;  // group id within this t-slice
    const int ngroups = (gridDim.x * blockDim.x) >> 5;
    const int t      = blockIdx.y;

    const float4* __restrict__ z4 = (const float4*)z;
    // per-type weight fragment: 32 float4 per type, L1-resident broadcast
    const float4  w  = ((const float4*)weight)[t * 32 + lane];

    const int*  src_t = edge_src + (size_t)t * E;
    const int*  dst_t = edge_dst + (size_t)t * E;
    float*      out_t = out      + (size_t)t * E;

    for (int e = gid; e < E; e += ngroups) {
        const int s = src_t[e];
        const int d = dst_t[e];
        const float4 a = z4[(size_t)s * 32 + lane];
        const float4 b = z4[(size_t)d * 32 + lane];
        float p = a.x * b.x * w.x
                + a.y * b.y * w.y
                + a.z * b.z * w.z
                + a.w * b.w * w.w;
        // reduce across the 32-lane group (xor masks < 32 stay within halves of the wave64)
        p += __shfl_xor(p, 16);
        p += __shfl_xor(p, 8);
        p += __shfl_xor(p, 4);
        p += __shfl_xor(p, 2);
        p += __shfl_xor(p, 1);
        if (lane == 0) {
            out_t[e] = 1.0f / (1.0f + __expf(-p));
        }
    }
}

extern "C" void kernel_launch(void* const* d_in, const int* in_sizes, int n_in,
                              void* d_out, int out_size, void* d_ws, size_t ws_size,
                              hipStream_t stream) {
    const float* z      = (const float*)d_in[0];
    const float* weight = (const float*)d_in[1];
    const int*   e_src  = (const int*)d_in[2];
    const int*   e_dst  = (const int*)d_in[3];
    float*       out    = (float*)d_out;

    const int IN_DIM = 128;
    const int T = in_sizes[1] / IN_DIM;          // 8 edge types
    const int E = in_sizes[2] / T;               // 100000 edges per type

    // memory-bound: cap total blocks ~2048-4096, grid-stride the rest
    dim3 block(256);
    dim3 grid(512, T);                            // 512*8 = 4096 blocks, 8 edge-groups/block
    hipLaunchKernelGGL(mipd_kernel, grid, block, 0, stream,
                       z, weight, e_src, e_dst, out, E);
}

// Round 2
// 70.236 us; speedup vs baseline: 1.6034x; 1.6034x over previous
//
#include <hip/hip_runtime.h>

typedef unsigned int   u32;
typedef unsigned short u16;

// round-to-nearest-even f32 -> bf16 bits
__device__ __forceinline__ u16 f2bf(float x) {
    u32 u = __builtin_bit_cast(u32, x);
    u = (u + 0x7fffu + ((u >> 16) & 1u)) >> 16;
    return (u16)u;
}
__device__ __forceinline__ float bf_lo(u32 q) {   // element 2k   (low 16 bits)
    return __builtin_bit_cast(float, q << 16);
}
__device__ __forceinline__ float bf_hi(u32 q) {   // element 2k+1 (high 16 bits)
    return __builtin_bit_cast(float, q & 0xffff0000u);
}

// Pass 1: z [N,128] f32 -> zb [N,128] bf16 (packed, 16 uint4 per row)
__global__ __launch_bounds__(256) void convert_z_kernel(
    const float* __restrict__ z, uint4* __restrict__ zb, int n8)  // n8 = N*128/8
{
    int i = blockIdx.x * blockDim.x + threadIdx.x;
    const int stride = gridDim.x * blockDim.x;
    const float4* __restrict__ z4 = (const float4*)z;
    for (; i < n8; i += stride) {
        float4 a = z4[2 * i];
        float4 b = z4[2 * i + 1];
        u32 p0 = (u32)f2bf(a.x) | ((u32)f2bf(a.y) << 16);
        u32 p1 = (u32)f2bf(a.z) | ((u32)f2bf(a.w) << 16);
        u32 p2 = (u32)f2bf(b.x) | ((u32)f2bf(b.y) << 16);
        u32 p3 = (u32)f2bf(b.z) | ((u32)f2bf(b.w) << 16);
        zb[i] = make_uint4(p0, p1, p2, p3);
    }
}

// Pass 2: 16 lanes per edge; lane `sub` loads uint4 (8 bf16) at row offset sub*16B.
// 16 lanes x 16 B = full 256 B bf16 row, coalesced. shfl_xor reduce over 16 lanes.
__global__ __launch_bounds__(256) void mipd_bf16_kernel(
    const uint4* __restrict__ zb,       // [N][16] uint4
    const float* __restrict__ weight,   // [T,128] f32
    const int*   __restrict__ edge_src,
    const int*   __restrict__ edge_dst,
    float*       __restrict__ out,
    int E)
{
    const int sub     = threadIdx.x & 15;
    const int gid     = (blockIdx.x * blockDim.x + threadIdx.x) >> 4;
    const int ngroups = (gridDim.x * blockDim.x) >> 4;
    const int t       = blockIdx.y;

    // this lane's 8 weights (f32), L1-resident
    const float4* w4 = (const float4*)(weight + (size_t)t * 128 + sub * 8);
    const float4 w0 = w4[0], w1 = w4[1];

    const int* src_t = edge_src + (size_t)t * E;
    const int* dst_t = edge_dst + (size_t)t * E;
    float*     out_t = out      + (size_t)t * E;

    for (int e = gid; e < E; e += ngroups) {
        const int s = src_t[e];
        const int d = dst_t[e];
        const uint4 A = zb[(size_t)s * 16 + sub];
        const uint4 B = zb[(size_t)d * 16 + sub];

        float p;
        p  = (bf_lo(A.x) * bf_lo(B.x)) * w0.x;
        p += (bf_hi(A.x) * bf_hi(B.x)) * w0.y;
        p += (bf_lo(A.y) * bf_lo(B.y)) * w0.z;
        p += (bf_hi(A.y) * bf_hi(B.y)) * w0.w;
        p += (bf_lo(A.z) * bf_lo(B.z)) * w1.x;
        p += (bf_hi(A.z) * bf_hi(B.z)) * w1.y;
        p += (bf_lo(A.w) * bf_lo(B.w)) * w1.z;
        p += (bf_hi(A.w) * bf_hi(B.w)) * w1.w;

        // reduce across the 16-lane group
        p += __shfl_xor(p, 8);
        p += __shfl_xor(p, 4);
        p += __shfl_xor(p, 2);
        p += __shfl_xor(p, 1);

        if (sub == 0) {
            out_t[e] = 1.0f / (1.0f + __expf(-p));
        }
    }
}

// f32 fallback (round-1 kernel) in case ws is too small for the bf16 copy.
__global__ __launch_bounds__(256) void mipd_f32_kernel(
    const float* __restrict__ z,
    const float* __restrict__ weight,
    const int*   __restrict__ edge_src,
    const int*   __restrict__ edge_dst,
    float*       __restrict__ out,
    int E)
{
    const int lane    = threadIdx.x & 31;
    const int gid     = (blockIdx.x * blockDim.x + threadIdx.x) >> 5;
    const int ngroups = (gridDim.x * blockDim.x) >> 5;
    const int t       = blockIdx.y;

    const float4* __restrict__ z4 = (const float4*)z;
    const float4  w = ((const float4*)weight)[t * 32 + lane];

    const int* src_t = edge_src + (size_t)t * E;
    const int* dst_t = edge_dst + (size_t)t * E;
    float*     out_t = out      + (size_t)t * E;

    for (int e = gid; e < E; e += ngroups) {
        const int s = src_t[e];
        const int d = dst_t[e];
        const float4 a = z4[(size_t)s * 32 + lane];
        const float4 b = z4[(size_t)d * 32 + lane];
        float p = a.x * b.x * w.x + a.y * b.y * w.y
                + a.z * b.z * w.z + a.w * b.w * w.w;
        p += __shfl_xor(p, 16);
        p += __shfl_xor(p, 8);
        p += __shfl_xor(p, 4);
        p += __shfl_xor(p, 2);
        p += __shfl_xor(p, 1);
        if (lane == 0) out_t[e] = 1.0f / (1.0f + __expf(-p));
    }
}

extern "C" void kernel_launch(void* const* d_in, const int* in_sizes, int n_in,
                              void* d_out, int out_size, void* d_ws, size_t ws_size,
                              hipStream_t stream) {
    const float* z      = (const float*)d_in[0];
    const float* weight = (const float*)d_in[1];
    const int*   e_src  = (const int*)d_in[2];
    const int*   e_dst  = (const int*)d_in[3];
    float*       out    = (float*)d_out;

    const int IN_DIM = 128;
    const int T = in_sizes[1] / IN_DIM;              // 8
    const int E = in_sizes[2] / T;                   // 100000
    const int N = in_sizes[0] / IN_DIM;              // 100000

    const size_t zb_bytes = (size_t)N * IN_DIM * 2;  // 25.6 MB

    if (ws_size >= zb_bytes) {
        uint4* zb = (uint4*)d_ws;
        const int n8 = N * IN_DIM / 8;               // 1.6M uint4 stores
        hipLaunchKernelGGL(convert_z_kernel, dim3(2048), dim3(256), 0, stream,
                           z, zb, n8);
        hipLaunchKernelGGL(mipd_bf16_kernel, dim3(256, T), dim3(256), 0, stream,
                           zb, weight, e_src, e_dst, out, E);
    } else {
        hipLaunchKernelGGL(mipd_f32_kernel, dim3(512, T), dim3(256), 0, stream,
                           z, weight, e_src, e_dst, out, E);
    }
}

// Round 3
// 68.169 us; speedup vs baseline: 1.6520x; 1.0303x over previous
//
#include <hip/hip_runtime.h>

typedef unsigned int   u32;
typedef unsigned short u16;

// round-to-nearest-even f32 -> bf16 bits
__device__ __forceinline__ u16 f2bf(float x) {
    u32 u = __builtin_bit_cast(u32, x);
    u = (u + 0x7fffu + ((u >> 16) & 1u)) >> 16;
    return (u16)u;
}
__device__ __forceinline__ float bf_lo(u32 q) { return __builtin_bit_cast(float, q << 16); }
__device__ __forceinline__ float bf_hi(u32 q) { return __builtin_bit_cast(float, q & 0xffff0000u); }

// Pass 1: z [N,128] f32 -> zb [N,128] bf16 (packed, 16 uint4 per row)
__global__ __launch_bounds__(256) void convert_z_kernel(
    const float* __restrict__ z, uint4* __restrict__ zb, int n8)
{
    int i = blockIdx.x * blockDim.x + threadIdx.x;
    const int stride = gridDim.x * blockDim.x;
    const float4* __restrict__ z4 = (const float4*)z;
    for (; i < n8; i += stride) {
        float4 a = z4[2 * i];
        float4 b = z4[2 * i + 1];
        u32 p0 = (u32)f2bf(a.x) | ((u32)f2bf(a.y) << 16);
        u32 p1 = (u32)f2bf(a.z) | ((u32)f2bf(a.w) << 16);
        u32 p2 = (u32)f2bf(b.x) | ((u32)f2bf(b.y) << 16);
        u32 p3 = (u32)f2bf(b.z) | ((u32)f2bf(b.w) << 16);
        zb[i] = make_uint4(p0, p1, p2, p3);
    }
}

__device__ __forceinline__ float dot8(const uint4& A, const uint4& B,
                                      const float4& w0, const float4& w1) {
    float p;
    p  = (bf_lo(A.x) * bf_lo(B.x)) * w0.x;
    p += (bf_hi(A.x) * bf_hi(B.x)) * w0.y;
    p += (bf_lo(A.y) * bf_lo(B.y)) * w0.z;
    p += (bf_hi(A.y) * bf_hi(B.y)) * w0.w;
    p += (bf_lo(A.z) * bf_lo(B.z)) * w1.x;
    p += (bf_hi(A.z) * bf_hi(B.z)) * w1.y;
    p += (bf_lo(A.w) * bf_lo(B.w)) * w1.z;
    p += (bf_hi(A.w) * bf_hi(B.w)) * w1.w;
    return p;
}

__device__ __forceinline__ float red16(float p) {
    p += __shfl_xor(p, 8);
    p += __shfl_xor(p, 4);
    p += __shfl_xor(p, 2);
    p += __shfl_xor(p, 1);
    return p;
}

// Pass 2 (x4-unrolled): 16 lanes per edge-quad. One int4 broadcast load per
// side yields 4 edges' indices; all 8 row-gathers issue back-to-back (4x the
// memory-level parallelism of the previous version); results written as one
// float4 from lane 0 of each group.
__global__ __launch_bounds__(256) void mipd_bf16_u4_kernel(
    const uint4* __restrict__ zb,       // [N][16] uint4 (bf16 rows)
    const float* __restrict__ weight,   // [T,128] f32
    const int*   __restrict__ edge_src,
    const int*   __restrict__ edge_dst,
    float*       __restrict__ out,
    int E4)                             // E/4 (E divisible by 4)
{
    const int sub     = threadIdx.x & 15;
    const int gid     = (blockIdx.x * blockDim.x + threadIdx.x) >> 4;
    const int ngroups = (gridDim.x * blockDim.x) >> 4;
    const int t       = blockIdx.y;
    const int E       = E4 * 4;

    const float4* w4 = (const float4*)(weight + (size_t)t * 128 + sub * 8);
    const float4 w0 = w4[0], w1 = w4[1];

    const int4* src4 = (const int4*)(edge_src + (size_t)t * E);
    const int4* dst4 = (const int4*)(edge_dst + (size_t)t * E);
    float4*     out4 = (float4*)(out + (size_t)t * E);

    for (int b = gid; b < E4; b += ngroups) {
        const int4 S = src4[b];
        const int4 D = dst4[b];

        const uint4 A0 = zb[(size_t)S.x * 16 + sub];
        const uint4 B0 = zb[(size_t)D.x * 16 + sub];
        const uint4 A1 = zb[(size_t)S.y * 16 + sub];
        const uint4 B1 = zb[(size_t)D.y * 16 + sub];
        const uint4 A2 = zb[(size_t)S.z * 16 + sub];
        const uint4 B2 = zb[(size_t)D.z * 16 + sub];
        const uint4 A3 = zb[(size_t)S.w * 16 + sub];
        const uint4 B3 = zb[(size_t)D.w * 16 + sub];

        float p0 = red16(dot8(A0, B0, w0, w1));
        float p1 = red16(dot8(A1, B1, w0, w1));
        float p2 = red16(dot8(A2, B2, w0, w1));
        float p3 = red16(dot8(A3, B3, w0, w1));

        if (sub == 0) {
            float4 r;
            r.x = 1.0f / (1.0f + __expf(-p0));
            r.y = 1.0f / (1.0f + __expf(-p1));
            r.z = 1.0f / (1.0f + __expf(-p2));
            r.w = 1.0f / (1.0f + __expf(-p3));
            out4[b] = r;
        }
    }
}

// Generic (non-unrolled) bf16 path for E % 4 != 0.
__global__ __launch_bounds__(256) void mipd_bf16_kernel(
    const uint4* __restrict__ zb,
    const float* __restrict__ weight,
    const int*   __restrict__ edge_src,
    const int*   __restrict__ edge_dst,
    float*       __restrict__ out,
    int E)
{
    const int sub     = threadIdx.x & 15;
    const int gid     = (blockIdx.x * blockDim.x + threadIdx.x) >> 4;
    const int ngroups = (gridDim.x * blockDim.x) >> 4;
    const int t       = blockIdx.y;

    const float4* w4 = (const float4*)(weight + (size_t)t * 128 + sub * 8);
    const float4 w0 = w4[0], w1 = w4[1];

    const int* src_t = edge_src + (size_t)t * E;
    const int* dst_t = edge_dst + (size_t)t * E;
    float*     out_t = out      + (size_t)t * E;

    for (int e = gid; e < E; e += ngroups) {
        const uint4 A = zb[(size_t)src_t[e] * 16 + sub];
        const uint4 B = zb[(size_t)dst_t[e] * 16 + sub];
        float p = red16(dot8(A, B, w0, w1));
        if (sub == 0) out_t[e] = 1.0f / (1.0f + __expf(-p));
    }
}

// f32 fallback if ws can't hold the bf16 copy.
__global__ __launch_bounds__(256) void mipd_f32_kernel(
    const float* __restrict__ z,
    const float* __restrict__ weight,
    const int*   __restrict__ edge_src,
    const int*   __restrict__ edge_dst,
    float*       __restrict__ out,
    int E)
{
    const int lane    = threadIdx.x & 31;
    const int gid     = (blockIdx.x * blockDim.x + threadIdx.x) >> 5;
    const int ngroups = (gridDim.x * blockDim.x) >> 5;
    const int t       = blockIdx.y;

    const float4* __restrict__ z4 = (const float4*)z;
    const float4  w = ((const float4*)weight)[t * 32 + lane];

    const int* src_t = edge_src + (size_t)t * E;
    const int* dst_t = edge_dst + (size_t)t * E;
    float*     out_t = out      + (size_t)t * E;

    for (int e = gid; e < E; e += ngroups) {
        const float4 a = z4[(size_t)src_t[e] * 32 + lane];
        const float4 b = z4[(size_t)dst_t[e] * 32 + lane];
        float p = a.x * b.x * w.x + a.y * b.y * w.y
                + a.z * b.z * w.z + a.w * b.w * w.w;
        p += __shfl_xor(p, 16);
        p += __shfl_xor(p, 8);
        p += __shfl_xor(p, 4);
        p += __shfl_xor(p, 2);
        p += __shfl_xor(p, 1);
        if (lane == 0) out_t[e] = 1.0f / (1.0f + __expf(-p));
    }
}

extern "C" void kernel_launch(void* const* d_in, const int* in_sizes, int n_in,
                              void* d_out, int out_size, void* d_ws, size_t ws_size,
                              hipStream_t stream) {
    const float* z      = (const float*)d_in[0];
    const float* weight = (const float*)d_in[1];
    const int*   e_src  = (const int*)d_in[2];
    const int*   e_dst  = (const int*)d_in[3];
    float*       out    = (float*)d_out;

    const int IN_DIM = 128;
    const int T = in_sizes[1] / IN_DIM;              // 8
    const int E = in_sizes[2] / T;                   // 100000
    const int N = in_sizes[0] / IN_DIM;              // 100000

    const size_t zb_bytes = (size_t)N * IN_DIM * 2;  // 25.6 MB

    if (ws_size >= zb_bytes) {
        uint4* zb = (uint4*)d_ws;
        const int n8 = N * IN_DIM / 8;
        hipLaunchKernelGGL(convert_z_kernel, dim3(2048), dim3(256), 0, stream,
                           z, zb, n8);
        if ((E & 3) == 0) {
            hipLaunchKernelGGL(mipd_bf16_u4_kernel, dim3(256, T), dim3(256), 0, stream,
                               zb, weight, e_src, e_dst, out, E >> 2);
        } else {
            hipLaunchKernelGGL(mipd_bf16_kernel, dim3(256, T), dim3(256), 0, stream,
                               zb, weight, e_src, e_dst, out, E);
        }
    } else {
        hipLaunchKernelGGL(mipd_f32_kernel, dim3(512, T), dim3(256), 0, stream,
                           z, weight, e_src, e_dst, out, E);
    }
}

// Round 4
// 66.154 us; speedup vs baseline: 1.7024x; 1.0305x over previous
//
#include <hip/hip_runtime.h>

typedef unsigned int   u32;
typedef unsigned short u16;

// round-to-nearest-even f32 -> bf16 bits
__device__ __forceinline__ u16 f2bf(float x) {
    u32 u = __builtin_bit_cast(u32, x);
    u = (u + 0x7fffu + ((u >> 16) & 1u)) >> 16;
    return (u16)u;
}
__device__ __forceinline__ float bf_lo(u32 q) { return __builtin_bit_cast(float, q << 16); }
__device__ __forceinline__ float bf_hi(u32 q) { return __builtin_bit_cast(float, q & 0xffff0000u); }

__device__ __forceinline__ float dot8(const uint4& A, const uint4& B,
                                      const float4& w0, const float4& w1) {
    float p;
    p  = (bf_lo(A.x) * bf_lo(B.x)) * w0.x;
    p += (bf_hi(A.x) * bf_hi(B.x)) * w0.y;
    p += (bf_lo(A.y) * bf_lo(B.y)) * w0.z;
    p += (bf_hi(A.y) * bf_hi(B.y)) * w0.w;
    p += (bf_lo(A.z) * bf_lo(B.z)) * w1.x;
    p += (bf_hi(A.z) * bf_hi(B.z)) * w1.y;
    p += (bf_lo(A.w) * bf_lo(B.w)) * w1.z;
    p += (bf_hi(A.w) * bf_hi(B.w)) * w1.w;
    return p;
}

__device__ __forceinline__ float red8(float p) {
    p += __shfl_xor(p, 4);
    p += __shfl_xor(p, 2);
    p += __shfl_xor(p, 1);
    return p;
}
__device__ __forceinline__ float red16(float p) {
    p += __shfl_xor(p, 8);
    return red8(p);
}

// Pass 0: z [N,128] f32 -> split bf16 halves:
//   zbL [N][8] uint4 = dims 0..63, zbH [N][8] uint4 = dims 64..127.
// Contiguous 12.8 MB per half so each gather pass touches a dense region.
__global__ __launch_bounds__(256) void convert_z_split_kernel(
    const float* __restrict__ z, uint4* __restrict__ zbL, uint4* __restrict__ zbH,
    int n16)  // N*16 uint4 blocks total
{
    int i = blockIdx.x * blockDim.x + threadIdx.x;
    const int stride = gridDim.x * blockDim.x;
    const float4* __restrict__ z4 = (const float4*)z;
    for (; i < n16; i += stride) {
        float4 a = z4[2 * i];
        float4 b = z4[2 * i + 1];
        u32 p0 = (u32)f2bf(a.x) | ((u32)f2bf(a.y) << 16);
        u32 p1 = (u32)f2bf(a.z) | ((u32)f2bf(a.w) << 16);
        u32 p2 = (u32)f2bf(b.x) | ((u32)f2bf(b.y) << 16);
        u32 p3 = (u32)f2bf(b.z) | ((u32)f2bf(b.w) << 16);
        const int r = i >> 4;         // node row
        const int j = i & 15;         // uint4 index within row (0..15)
        if (j < 8) zbL[r * 8 + j]       = make_uint4(p0, p1, p2, p3);
        else       zbH[r * 8 + (j - 8)] = make_uint4(p0, p1, p2, p3);
    }
}

// Gather pass over one 64-dim half. 8 lanes per edge, 4 edges per group
// (int4 index broadcast, 8 row-gathers of 128B back-to-back).
// PASS 0: dims 0..63, writes partial sums.
// PASS 1: dims 64..127, adds partials, sigmoid, writes out.
template <int PASS>
__global__ __launch_bounds__(256) void mipd_half_kernel(
    const uint4* __restrict__ zh,       // [N][8] uint4 (one bf16 half)
    const float* __restrict__ weight,   // [T,128] f32
    const int*   __restrict__ edge_src,
    const int*   __restrict__ edge_dst,
    float*       __restrict__ part,     // [T*E] f32 partials
    float*       __restrict__ out,
    int E4)                             // E/4
{
    const int sub     = threadIdx.x & 7;
    const int gid     = (blockIdx.x * blockDim.x + threadIdx.x) >> 3;
    const int ngroups = (gridDim.x * blockDim.x) >> 3;
    const int t       = blockIdx.y;
    const int E       = E4 * 4;

    const float4* w4 = (const float4*)(weight + (size_t)t * 128 + PASS * 64 + sub * 8);
    const float4 w0 = w4[0], w1 = w4[1];

    const int4* src4 = (const int4*)(edge_src + (size_t)t * E);
    const int4* dst4 = (const int4*)(edge_dst + (size_t)t * E);
    float4*     par4 = (float4*)(part + (size_t)t * E);
    float4*     out4 = (float4*)(out + (size_t)t * E);

    for (int b = gid; b < E4; b += ngroups) {
        const int4 S = src4[b];
        const int4 D = dst4[b];

        const uint4 A0 = zh[(size_t)S.x * 8 + sub];
        const uint4 B0 = zh[(size_t)D.x * 8 + sub];
        const uint4 A1 = zh[(size_t)S.y * 8 + sub];
        const uint4 B1 = zh[(size_t)D.y * 8 + sub];
        const uint4 A2 = zh[(size_t)S.z * 8 + sub];
        const uint4 B2 = zh[(size_t)D.z * 8 + sub];
        const uint4 A3 = zh[(size_t)S.w * 8 + sub];
        const uint4 B3 = zh[(size_t)D.w * 8 + sub];

        float p0 = red8(dot8(A0, B0, w0, w1));
        float p1 = red8(dot8(A1, B1, w0, w1));
        float p2 = red8(dot8(A2, B2, w0, w1));
        float p3 = red8(dot8(A3, B3, w0, w1));

        if (sub == 0) {
            if (PASS == 0) {
                par4[b] = make_float4(p0, p1, p2, p3);
            } else {
                const float4 q = par4[b];
                float4 r;
                r.x = 1.0f / (1.0f + __expf(-(p0 + q.x)));
                r.y = 1.0f / (1.0f + __expf(-(p1 + q.y)));
                r.z = 1.0f / (1.0f + __expf(-(p2 + q.z)));
                r.w = 1.0f / (1.0f + __expf(-(p3 + q.w)));
                out4[b] = r;
            }
        }
    }
}

// ---------- fallback path: single-pass bf16 (round-3 kernel) ----------
__global__ __launch_bounds__(256) void convert_z_kernel(
    const float* __restrict__ z, uint4* __restrict__ zb, int n8)
{
    int i = blockIdx.x * blockDim.x + threadIdx.x;
    const int stride = gridDim.x * blockDim.x;
    const float4* __restrict__ z4 = (const float4*)z;
    for (; i < n8; i += stride) {
        float4 a = z4[2 * i];
        float4 b = z4[2 * i + 1];
        u32 p0 = (u32)f2bf(a.x) | ((u32)f2bf(a.y) << 16);
        u32 p1 = (u32)f2bf(a.z) | ((u32)f2bf(a.w) << 16);
        u32 p2 = (u32)f2bf(b.x) | ((u32)f2bf(b.y) << 16);
        u32 p3 = (u32)f2bf(b.z) | ((u32)f2bf(b.w) << 16);
        zb[i] = make_uint4(p0, p1, p2, p3);
    }
}

__global__ __launch_bounds__(256) void mipd_bf16_u4_kernel(
    const uint4* __restrict__ zb,
    const float* __restrict__ weight,
    const int*   __restrict__ edge_src,
    const int*   __restrict__ edge_dst,
    float*       __restrict__ out,
    int E4)
{
    const int sub     = threadIdx.x & 15;
    const int gid     = (blockIdx.x * blockDim.x + threadIdx.x) >> 4;
    const int ngroups = (gridDim.x * blockDim.x) >> 4;
    const int t       = blockIdx.y;
    const int E       = E4 * 4;

    const float4* w4 = (const float4*)(weight + (size_t)t * 128 + sub * 8);
    const float4 w0 = w4[0], w1 = w4[1];

    const int4* src4 = (const int4*)(edge_src + (size_t)t * E);
    const int4* dst4 = (const int4*)(edge_dst + (size_t)t * E);
    float4*     out4 = (float4*)(out + (size_t)t * E);

    for (int b = gid; b < E4; b += ngroups) {
        const int4 S = src4[b];
        const int4 D = dst4[b];
        const uint4 A0 = zb[(size_t)S.x * 16 + sub];
        const uint4 B0 = zb[(size_t)D.x * 16 + sub];
        const uint4 A1 = zb[(size_t)S.y * 16 + sub];
        const uint4 B1 = zb[(size_t)D.y * 16 + sub];
        const uint4 A2 = zb[(size_t)S.z * 16 + sub];
        const uint4 B2 = zb[(size_t)D.z * 16 + sub];
        const uint4 A3 = zb[(size_t)S.w * 16 + sub];
        const uint4 B3 = zb[(size_t)D.w * 16 + sub];

        float p0 = red16(dot8(A0, B0, w0, w1));
        float p1 = red16(dot8(A1, B1, w0, w1));
        float p2 = red16(dot8(A2, B2, w0, w1));
        float p3 = red16(dot8(A3, B3, w0, w1));

        if (sub == 0) {
            float4 r;
            r.x = 1.0f / (1.0f + __expf(-p0));
            r.y = 1.0f / (1.0f + __expf(-p1));
            r.z = 1.0f / (1.0f + __expf(-p2));
            r.w = 1.0f / (1.0f + __expf(-p3));
            out4[b] = r;
        }
    }
}

__global__ __launch_bounds__(256) void mipd_f32_kernel(
    const float* __restrict__ z,
    const float* __restrict__ weight,
    const int*   __restrict__ edge_src,
    const int*   __restrict__ edge_dst,
    float*       __restrict__ out,
    int E)
{
    const int lane    = threadIdx.x & 31;
    const int gid     = (blockIdx.x * blockDim.x + threadIdx.x) >> 5;
    const int ngroups = (gridDim.x * blockDim.x) >> 5;
    const int t       = blockIdx.y;

    const float4* __restrict__ z4 = (const float4*)z;
    const float4  w = ((const float4*)weight)[t * 32 + lane];

    const int* src_t = edge_src + (size_t)t * E;
    const int* dst_t = edge_dst + (size_t)t * E;
    float*     out_t = out      + (size_t)t * E;

    for (int e = gid; e < E; e += ngroups) {
        const float4 a = z4[(size_t)src_t[e] * 32 + lane];
        const float4 b = z4[(size_t)dst_t[e] * 32 + lane];
        float p = a.x * b.x * w.x + a.y * b.y * w.y
                + a.z * b.z * w.z + a.w * b.w * w.w;
        p += __shfl_xor(p, 16);
        p += __shfl_xor(p, 8);
        p += __shfl_xor(p, 4);
        p += __shfl_xor(p, 2);
        p += __shfl_xor(p, 1);
        if (lane == 0) out_t[e] = 1.0f / (1.0f + __expf(-p));
    }
}

extern "C" void kernel_launch(void* const* d_in, const int* in_sizes, int n_in,
                              void* d_out, int out_size, void* d_ws, size_t ws_size,
                              hipStream_t stream) {
    const float* z      = (const float*)d_in[0];
    const float* weight = (const float*)d_in[1];
    const int*   e_src  = (const int*)d_in[2];
    const int*   e_dst  = (const int*)d_in[3];
    float*       out    = (float*)d_out;

    const int IN_DIM = 128;
    const int T = in_sizes[1] / IN_DIM;              // 8
    const int E = in_sizes[2] / T;                   // 100000
    const int N = in_sizes[0] / IN_DIM;              // 100000

    const size_t half_bytes  = (size_t)N * 64 * 2;   // 12.8 MB per half
    const size_t part_bytes  = (size_t)T * E * 4;    // 3.2 MB partials
    const size_t split_need  = 2 * half_bytes + part_bytes;   // 28.8 MB
    const size_t single_need = (size_t)N * IN_DIM * 2;        // 25.6 MB

    if (ws_size >= split_need && (E & 3) == 0) {
        uint4* zbL  = (uint4*)d_ws;
        uint4* zbH  = zbL + (size_t)N * 8;
        float* part = (float*)(zbH + (size_t)N * 8);
        const int n16 = N * 16;
        hipLaunchKernelGGL(convert_z_split_kernel, dim3(2048), dim3(256), 0, stream,
                           z, zbL, zbH, n16);
        hipLaunchKernelGGL((mipd_half_kernel<0>), dim3(256, T), dim3(256), 0, stream,
                           zbL, weight, e_src, e_dst, part, out, E >> 2);
        hipLaunchKernelGGL((mipd_half_kernel<1>), dim3(256, T), dim3(256), 0, stream,
                           zbH, weight, e_src, e_dst, part, out, E >> 2);
    } else if (ws_size >= single_need && (E & 3) == 0) {
        uint4* zb = (uint4*)d_ws;
        hipLaunchKernelGGL(convert_z_kernel, dim3(2048), dim3(256), 0, stream,
                           z, zb, N * IN_DIM / 8);
        hipLaunchKernelGGL(mipd_bf16_u4_kernel, dim3(256, T), dim3(256), 0, stream,
                           zb, weight, e_src, e_dst, out, E >> 2);
    } else {
        hipLaunchKernelGGL(mipd_f32_kernel, dim3(512, T), dim3(256), 0, stream,
                           z, weight, e_src, e_dst, out, E);
    }
}